// Round 1
// baseline (6498.001 us; speedup 1.0000x reference)
//
#include <hip/hip_runtime.h>
#include <math.h>

#define DIM 512
#define NSP 513                 // spatial seq len (MAX_S+1)
#define BATCHB 2
#define SP_ROWS (BATCHB*NSP)    // 1026
#define DP_ROWS (SP_ROWS*5)     // 5130
#define OUT_ROWS (BATCHB*2048)  // 4096
#define VOCABN 16384

// ---------------- GEMM: C = act(A@B + bias) + res ----------------
// A[M,K], B[K,N] row-major. BM=BN=128, BK=16, 256 threads, 8x8 microtile.
__global__ __launch_bounds__(256) void gemm_f32(
    const float* __restrict__ A, const float* __restrict__ B,
    const float* __restrict__ bias, const float* __restrict__ res,
    float* __restrict__ C, int M, int N, int K, int act)
{
  __shared__ float As[16][128];
  __shared__ float Bs[16][128];
  int tid = threadIdx.x;
  int row0 = blockIdx.y * 128;
  int col0 = blockIdx.x * 128;
  int tx = tid & 15, ty = tid >> 4;
  float acc[8][8];
#pragma unroll
  for (int i = 0; i < 8; ++i)
#pragma unroll
    for (int j = 0; j < 8; ++j) acc[i][j] = 0.f;

  for (int k0 = 0; k0 < K; k0 += 16) {
#pragma unroll
    for (int l = 0; l < 2; ++l) {
      int idx = tid + l * 256;
      int ar = idx >> 2;            // 0..127
      int ak = (idx & 3) << 2;      // 0,4,8,12
      float4 av = make_float4(0.f, 0.f, 0.f, 0.f);
      int gr = row0 + ar;
      if (gr < M) av = *(const float4*)(A + (size_t)gr * K + k0 + ak);
      As[ak + 0][ar] = av.x; As[ak + 1][ar] = av.y;
      As[ak + 2][ar] = av.z; As[ak + 3][ar] = av.w;
      int br = idx >> 5;            // 0..15
      int bc = (idx & 31) << 2;     // 0..124
      float4 bv = *(const float4*)(B + (size_t)(k0 + br) * N + col0 + bc);
      *(float4*)(&Bs[br][bc]) = bv;
    }
    __syncthreads();
#pragma unroll
    for (int k = 0; k < 16; ++k) {
      float a[8], b[8];
      *(float4*)(a)     = *(const float4*)(&As[k][ty * 8]);
      *(float4*)(a + 4) = *(const float4*)(&As[k][ty * 8 + 4]);
      *(float4*)(b)     = *(const float4*)(&Bs[k][tx * 8]);
      *(float4*)(b + 4) = *(const float4*)(&Bs[k][tx * 8 + 4]);
#pragma unroll
      for (int i = 0; i < 8; ++i)
#pragma unroll
        for (int j = 0; j < 8; ++j) acc[i][j] = fmaf(a[i], b[j], acc[i][j]);
    }
    __syncthreads();
  }
#pragma unroll
  for (int i = 0; i < 8; ++i) {
    int r = row0 + ty * 8 + i;
    if (r >= M) break;
#pragma unroll
    for (int j = 0; j < 8; ++j) {
      int c = col0 + tx * 8 + j;
      float v = acc[i][j];
      if (bias) v += bias[c];
      if (act) v = 0.5f * v * (1.0f + erff(v * 0.70710678118f)); // exact gelu
      if (res) v += res[(size_t)r * N + c];
      C[(size_t)r * N + c] = v;
    }
  }
}

// ---------------- LayerNorm over 512, one wave per row ----------------
__global__ __launch_bounds__(64) void layernorm512(
    const float* __restrict__ in, float* __restrict__ out,
    const float* __restrict__ g, const float* __restrict__ bb)
{
  int row = blockIdx.x;
  int t = threadIdx.x;
  const float* x = in + (size_t)row * DIM;
  float xa[8];
  *(float4*)(xa)     = *(const float4*)(x + t * 4);
  *(float4*)(xa + 4) = *(const float4*)(x + 256 + t * 4);
  float s = 0.f, sq = 0.f;
#pragma unroll
  for (int i = 0; i < 8; ++i) { s += xa[i]; sq += xa[i] * xa[i]; }
#pragma unroll
  for (int off = 32; off; off >>= 1) { s += __shfl_xor(s, off); sq += __shfl_xor(sq, off); }
  float mean = s * (1.f / 512.f);
  float var = sq * (1.f / 512.f) - mean * mean;
  float rs = rsqrtf(var + 1e-5f);
  float ga[8], ba[8];
  *(float4*)(ga)     = *(const float4*)(g + t * 4);
  *(float4*)(ga + 4) = *(const float4*)(g + 256 + t * 4);
  *(float4*)(ba)     = *(const float4*)(bb + t * 4);
  *(float4*)(ba + 4) = *(const float4*)(bb + 256 + t * 4);
  float oa[8];
#pragma unroll
  for (int i = 0; i < 8; ++i) oa[i] = (xa[i] - mean) * rs * ga[i] + ba[i];
  float* y = out + (size_t)row * DIM;
  *(float4*)(y + t * 4)       = *(const float4*)(oa);
  *(float4*)(y + 256 + t * 4) = *(const float4*)(oa + 4);
}

// ---------------- Embedding: tokens[r] = tok_emb[ids[r]] + dp_pos[r%4] ----------------
__global__ __launch_bounds__(128) void embed_tokens(
    const int* __restrict__ ids, const float* __restrict__ tok_emb,
    const float* __restrict__ dp_pos, float* __restrict__ tokens)
{
  int r = blockIdx.x;           // 0..4095 = b*2048 + s*4 + d
  int dpt = r & 3;
  int id = ids[r];
  int c = threadIdx.x * 4;
  float4 e = *(const float4*)(tok_emb + (size_t)id * 512 + c);
  float4 p = *(const float4*)(dp_pos + dpt * 512 + c);
  float4 o = make_float4(e.x + p.x, e.y + p.y, e.z + p.z, e.w + p.w);
  *(float4*)(tokens + (size_t)r * 512 + c) = o;
}

// ---------------- spatial input rows ----------------
__global__ __launch_bounds__(128) void spatial_init(
    const float* __restrict__ tokens, const float* __restrict__ sp_pos,
    const float* __restrict__ start_tok, float* __restrict__ x_sp)
{
  int r = blockIdx.x;           // 0..1025
  int b = r / NSP, s = r % NSP;
  int c = threadIdx.x * 4;
  float4 o;
  if (s == 0) {
    o = *(const float4*)(start_tok + c);
  } else {
    int s0 = s - 1;
    const float* tb = tokens + ((size_t)(b * 512 + s0) * 4) * 512 + c;
    float4 t0 = *(const float4*)(tb);
    float4 t1 = *(const float4*)(tb + 512);
    float4 t2 = *(const float4*)(tb + 1024);
    float4 t3 = *(const float4*)(tb + 1536);
    float4 pp = *(const float4*)(sp_pos + (size_t)s0 * 512 + c);
    o = make_float4(t0.x + t1.x + t2.x + t3.x + pp.x,
                    t0.y + t1.y + t2.y + t3.y + pp.y,
                    t0.z + t1.z + t2.z + t3.z + pp.z,
                    t0.w + t1.w + t2.w + t3.w + pp.w);
  }
  *(float4*)(x_sp + (size_t)r * 512 + c) = o;
}

// ---------------- spatial attention: scores+softmax into P ----------------
__global__ __launch_bounds__(256) void attn_sp_scores(
    const float* __restrict__ qkv, float* __restrict__ P)
{
  int i = blockIdx.x;        // query row 0..512
  int bh = blockIdx.y;       // b*8+h
  int b = bh >> 3, h = bh & 7;
  int tid = threadIdx.x;
  __shared__ float q[64];
  __shared__ float red[256];
  const float* qrow = qkv + (size_t)(b * NSP + i) * 1536 + h * 64;
  if (tid < 64) q[tid] = qrow[tid] * 0.125f;   // 1/sqrt(64)
  __syncthreads();
  float sc[3];
  float mymax = -3.0e38f;
#pragma unroll
  for (int jj = 0; jj < 3; ++jj) {
    int j = tid + jj * 256;
    float sv = -3.0e38f;
    if (j <= i) {
      const float* krow = qkv + (size_t)(b * NSP + j) * 1536 + 512 + h * 64;
      float acc = 0.f;
#pragma unroll
      for (int d4 = 0; d4 < 16; ++d4) {
        float4 kv = *(const float4*)(krow + d4 * 4);
        float4 qv = *(const float4*)(&q[d4 * 4]);
        acc += qv.x * kv.x + qv.y * kv.y + qv.z * kv.z + qv.w * kv.w;
      }
      sv = acc;
      mymax = fmaxf(mymax, sv);
    }
    sc[jj] = sv;
  }
  red[tid] = mymax; __syncthreads();
  for (int st = 128; st > 0; st >>= 1) { if (tid < st) red[tid] = fmaxf(red[tid], red[tid + st]); __syncthreads(); }
  float bmax = red[0]; __syncthreads();
  float mysum = 0.f;
#pragma unroll
  for (int jj = 0; jj < 3; ++jj) {
    int j = tid + jj * 256;
    if (j <= i) { sc[jj] = expf(sc[jj] - bmax); mysum += sc[jj]; }
    else sc[jj] = 0.f;
  }
  red[tid] = mysum; __syncthreads();
  for (int st = 128; st > 0; st >>= 1) { if (tid < st) red[tid] += red[tid + st]; __syncthreads(); }
  float inv = 1.0f / red[0];
  float* prow = P + ((size_t)bh * NSP + i) * NSP;
#pragma unroll
  for (int jj = 0; jj < 3; ++jj) {
    int j = tid + jj * 256;
    if (j < NSP) prow[j] = (j <= i) ? sc[jj] * inv : 0.f;
  }
}

// ---------------- spatial attention: O = P @ V ----------------
__global__ __launch_bounds__(256) void attn_sp_pv(
    const float* __restrict__ qkv, const float* __restrict__ P, float* __restrict__ O)
{
  int row = blockIdx.x;   // 0..1025
  int b = row / NSP, i = row % NSP;
  int tid = threadIdx.x;
#pragma unroll
  for (int cc = 0; cc < 2; ++cc) {
    int c = tid + cc * 256;
    int h = c >> 6, d = c & 63;
    const float* prow = P + ((size_t)(b * 8 + h) * NSP + i) * NSP;
    const float* vbase = qkv + (size_t)(b * NSP) * 1536 + 1024 + h * 64 + d;
    float acc = 0.f;
    for (int j = 0; j <= i; ++j) acc = fmaf(prow[j], vbase[(size_t)j * 1536], acc);
    O[(size_t)row * 512 + c] = acc;
  }
}

// ---------------- depth attention (N=5), one wave per (r,h) ----------------
__global__ __launch_bounds__(64) void attn_dp(
    const float* __restrict__ qkv, float* __restrict__ O)
{
  int r = blockIdx.x;     // 0..1025
  int h = blockIdx.y;
  int d = threadIdx.x;    // 0..63
  const float* base = qkv + (size_t)r * 5 * 1536 + h * 64 + d;
  float q[5], k[5], v[5];
#pragma unroll
  for (int p = 0; p < 5; ++p) {
    q[p] = base[p * 1536] * 0.125f;
    k[p] = base[p * 1536 + 512];
    v[p] = base[p * 1536 + 1024];
  }
#pragma unroll
  for (int i = 0; i < 5; ++i) {
    float s[5];
    float mx = -3.0e38f;
    for (int j = 0; j <= i; ++j) {
      float part = q[i] * k[j];
#pragma unroll
      for (int off = 32; off; off >>= 1) part += __shfl_xor(part, off);
      s[j] = part;
      mx = fmaxf(mx, part);
    }
    float sum = 0.f;
    for (int j = 0; j <= i; ++j) { s[j] = expf(s[j] - mx); sum += s[j]; }
    float invs = 1.0f / sum;
    float o = 0.f;
    for (int j = 0; j <= i; ++j) o += s[j] * v[j];
    O[((size_t)r * 5 + i) * 512 + h * 64 + d] = o * invs;
  }
}

// ---------------- build depth-transformer input ----------------
__global__ __launch_bounds__(128) void build_dt(
    const float* __restrict__ sp_final, const float* __restrict__ tokens,
    float* __restrict__ x_dp)
{
  int row = blockIdx.x;      // 0..5129
  int r = row / 5, cpos = row % 5;
  int c = threadIdx.x * 4;
  float4 o = make_float4(0.f, 0.f, 0.f, 0.f);
  if (cpos == 0) {
    o = *(const float4*)(sp_final + (size_t)r * 512 + c);
  } else {
    int b = r / NSP, sp = r % NSP;
    if (sp < 512)
      o = *(const float4*)(tokens + ((size_t)((b * 512 + sp) * 4 + (cpos - 1))) * 512 + c);
  }
  *(float4*)(x_dp + (size_t)row * 512 + c) = o;
}

// ---------------- gather rows needed for logits ----------------
__global__ __launch_bounds__(128) void gather_rows(
    const float* __restrict__ xn, float* __restrict__ dtg)
{
  int m = blockIdx.x;       // 0..4095
  int b = m >> 11;
  int t = 1 + (m & 2047);
  int c = threadIdx.x * 4;
  *(float4*)(dtg + (size_t)m * 512 + c) =
      *(const float4*)(xn + ((size_t)b * 2565 + t) * 512 + c);
}

extern "C" void kernel_launch(void* const* d_in, const int* in_sizes, int n_in,
                              void* d_out, int out_size, void* d_ws, size_t ws_size,
                              hipStream_t stream)
{
  const int*   ids       = (const int*)  d_in[0];
  const float* tok_emb   = (const float*)d_in[1];
  const float* start_tok = (const float*)d_in[2];
  const float* sp_pos    = (const float*)d_in[3];
  const float* dp_pos    = (const float*)d_in[4];
  const float* w_logit   = (const float*)d_in[5];
  const float* b_logit   = (const float*)d_in[6];
  const float* sp_ln1g = (const float*)d_in[7];
  const float* sp_ln1b = (const float*)d_in[8];
  const float* sp_qkv  = (const float*)d_in[9];
  const float* sp_wo   = (const float*)d_in[10];
  const float* sp_ln2g = (const float*)d_in[11];
  const float* sp_ln2b = (const float*)d_in[12];
  const float* sp_w1   = (const float*)d_in[13];
  const float* sp_b1   = (const float*)d_in[14];
  const float* sp_w2   = (const float*)d_in[15];
  const float* sp_b2   = (const float*)d_in[16];
  const float* sp_lnfg = (const float*)d_in[17];
  const float* sp_lnfb = (const float*)d_in[18];
  const float* dp_ln1g = (const float*)d_in[19];
  const float* dp_ln1b = (const float*)d_in[20];
  const float* dp_qkv  = (const float*)d_in[21];
  const float* dp_wo   = (const float*)d_in[22];
  const float* dp_ln2g = (const float*)d_in[23];
  const float* dp_ln2b = (const float*)d_in[24];
  const float* dp_w1   = (const float*)d_in[25];
  const float* dp_b1   = (const float*)d_in[26];
  const float* dp_w2   = (const float*)d_in[27];
  const float* dp_b2   = (const float*)d_in[28];
  const float* dp_lnfg = (const float*)d_in[29];
  const float* dp_lnfb = (const float*)d_in[30];

  float* ws = (float*)d_ws;
  float* tokens = ws; ws += (size_t)4096 * 512;
  float* x_sp   = ws; ws += (size_t)SP_ROWS * 512;
  float* x_dp   = ws; ws += (size_t)DP_ROWS * 512;
  float* xn     = ws; ws += (size_t)DP_ROWS * 512;
  float* qkvb   = ws; ws += (size_t)DP_ROWS * 1536;
  float* attno  = ws; ws += (size_t)DP_ROWS * 512;
  float* ffh    = ws; ws += (size_t)DP_ROWS * 2048;
  float* P      = ws; ws += (size_t)16 * NSP * NSP;
  float* dtg    = ws; ws += (size_t)OUT_ROWS * 512;

  auto gemm = [&](const float* A, const float* B, const float* bias, const float* res,
                  float* C, int M, int N, int K, int act) {
    dim3 g(N / 128, (M + 127) / 128);
    gemm_f32<<<g, 256, 0, stream>>>(A, B, bias, res, C, M, N, K, act);
  };

  embed_tokens<<<4096, 128, 0, stream>>>(ids, tok_emb, dp_pos, tokens);
  spatial_init<<<SP_ROWS, 128, 0, stream>>>(tokens, sp_pos, start_tok, x_sp);

  for (int l = 0; l < 4; ++l) {
    layernorm512<<<SP_ROWS, 64, 0, stream>>>(x_sp, xn, sp_ln1g + l * 512, sp_ln1b + l * 512);
    gemm(xn, sp_qkv + (size_t)l * 512 * 1536, nullptr, nullptr, qkvb, SP_ROWS, 1536, 512, 0);
    attn_sp_scores<<<dim3(NSP, 16), 256, 0, stream>>>(qkvb, P);
    attn_sp_pv<<<SP_ROWS, 256, 0, stream>>>(qkvb, P, attno);
    gemm(attno, sp_wo + (size_t)l * 512 * 512, nullptr, x_sp, x_sp, SP_ROWS, 512, 512, 0);
    layernorm512<<<SP_ROWS, 64, 0, stream>>>(x_sp, xn, sp_ln2g + l * 512, sp_ln2b + l * 512);
    gemm(xn, sp_w1 + (size_t)l * 512 * 2048, sp_b1 + l * 2048, nullptr, ffh, SP_ROWS, 2048, 512, 1);
    gemm(ffh, sp_w2 + (size_t)l * 2048 * 512, sp_b2 + l * 512, x_sp, x_sp, SP_ROWS, 512, 2048, 0);
  }
  layernorm512<<<SP_ROWS, 64, 0, stream>>>(x_sp, xn, sp_lnfg, sp_lnfb);
  build_dt<<<DP_ROWS, 128, 0, stream>>>(xn, tokens, x_dp);

  for (int l = 0; l < 2; ++l) {
    layernorm512<<<DP_ROWS, 64, 0, stream>>>(x_dp, xn, dp_ln1g + l * 512, dp_ln1b + l * 512);
    gemm(xn, dp_qkv + (size_t)l * 512 * 1536, nullptr, nullptr, qkvb, DP_ROWS, 1536, 512, 0);
    attn_dp<<<dim3(SP_ROWS, 8), 64, 0, stream>>>(qkvb, attno);
    gemm(attno, dp_wo + (size_t)l * 512 * 512, nullptr, x_dp, x_dp, DP_ROWS, 512, 512, 0);
    layernorm512<<<DP_ROWS, 64, 0, stream>>>(x_dp, xn, dp_ln2g + l * 512, dp_ln2b + l * 512);
    gemm(xn, dp_w1 + (size_t)l * 512 * 2048, dp_b1 + l * 2048, nullptr, ffh, DP_ROWS, 2048, 512, 1);
    gemm(ffh, dp_w2 + (size_t)l * 2048 * 512, dp_b2 + l * 512, x_dp, x_dp, DP_ROWS, 512, 2048, 0);
  }
  layernorm512<<<DP_ROWS, 64, 0, stream>>>(x_dp, xn, dp_lnfg, dp_lnfb);
  gather_rows<<<OUT_ROWS, 128, 0, stream>>>(xn, dtg);
  gemm(dtg, w_logit, b_logit, nullptr, (float*)d_out, OUT_ROWS, VOCABN, 512, 0);
}

// Round 2
// 2606.315 us; speedup vs baseline: 2.4932x; 2.4932x over previous
//
#include <hip/hip_runtime.h>
#include <math.h>

#define DIM 512
#define NSP 513                 // spatial seq len (MAX_S+1)
#define BATCHB 2
#define SP_ROWS (BATCHB*NSP)    // 1026
#define DP_ROWS (SP_ROWS*5)     // 5130
#define OUT_ROWS (BATCHB*2048)  // 4096
#define VOCABN 16384

typedef _Float16 f16x8 __attribute__((ext_vector_type(8)));
typedef _Float16 f16x4 __attribute__((ext_vector_type(4)));
typedef float    f32x4 __attribute__((ext_vector_type(4)));

#define LDK 40   // 32 + 8 fp16 pad (16B) -> 80B row stride in LDS

// ---------------- fp16 MFMA GEMM: C = act(A@B^T' + bias) + res ----------------
// A[M][K] fp16 row-major, Bt[N][K] fp16 row-major (weights pre-transposed).
// 128x128 tile, BK=32, 256 threads = 4 waves, each wave 64x64 (4x4 16x16x32 frags).
__global__ __launch_bounds__(256) void gemm_h(
    const _Float16* __restrict__ A, const _Float16* __restrict__ Bt,
    const float* __restrict__ bias, const float* __restrict__ res,
    float* __restrict__ Cf, _Float16* __restrict__ Ch,
    int M, int N, int K, int act)
{
  __shared__ __align__(16) _Float16 As[128 * LDK];
  __shared__ __align__(16) _Float16 Bs[128 * LDK];
  int tid = threadIdx.x;
  int wid = tid >> 6, lane = tid & 63;
  int row0 = blockIdx.y * 128, col0 = blockIdx.x * 128;
  int wr = (wid >> 1) * 64, wc = (wid & 1) * 64;

  // staging: thread t loads 16 fp16 of row ar at k-offset kh
  int ar = tid >> 1;
  int kh = (tid & 1) * 16;
  int arow = row0 + ar; if (arow > M - 1) arow = M - 1;
  bool aval = (row0 + ar) < M;
  const _Float16* Ap = A + (size_t)arow * K + kh;
  const _Float16* Bp = Bt + (size_t)(col0 + ar) * K + kh;

  f16x8 za;
#pragma unroll
  for (int i = 0; i < 8; ++i) za[i] = (_Float16)0.f;
  f32x4 acc[4][4];
#pragma unroll
  for (int m = 0; m < 4; ++m)
#pragma unroll
    for (int n = 0; n < 4; ++n) acc[m][n] = 0.f;

  const int nt = K >> 5;
  f16x8 ra0 = aval ? *(const f16x8*)(Ap) : za;
  f16x8 ra1 = aval ? *(const f16x8*)(Ap + 8) : za;
  f16x8 rb0 = *(const f16x8*)(Bp);
  f16x8 rb1 = *(const f16x8*)(Bp + 8);

  for (int t = 0; t < nt; ++t) {
    *(f16x8*)(&As[ar * LDK + kh])     = ra0;
    *(f16x8*)(&As[ar * LDK + kh + 8]) = ra1;
    *(f16x8*)(&Bs[ar * LDK + kh])     = rb0;
    *(f16x8*)(&Bs[ar * LDK + kh + 8]) = rb1;
    __syncthreads();
    if (t + 1 < nt) {
      const _Float16* Ap2 = Ap + (t + 1) * 32;
      const _Float16* Bp2 = Bp + (t + 1) * 32;
      ra0 = aval ? *(const f16x8*)(Ap2) : za;
      ra1 = aval ? *(const f16x8*)(Ap2 + 8) : za;
      rb0 = *(const f16x8*)(Bp2);
      rb1 = *(const f16x8*)(Bp2 + 8);
    }
    f16x8 af[4], bf[4];
#pragma unroll
    for (int m = 0; m < 4; ++m)
      af[m] = *(const f16x8*)(&As[(wr + m * 16 + (lane & 15)) * LDK + ((lane >> 4) << 3)]);
#pragma unroll
    for (int n = 0; n < 4; ++n)
      bf[n] = *(const f16x8*)(&Bs[(wc + n * 16 + (lane & 15)) * LDK + ((lane >> 4) << 3)]);
#pragma unroll
    for (int m = 0; m < 4; ++m)
#pragma unroll
      for (int n = 0; n < 4; ++n)
        acc[m][n] = __builtin_amdgcn_mfma_f32_16x16x32_f16(af[m], bf[n], acc[m][n], 0, 0, 0);
    __syncthreads();
  }

#pragma unroll
  for (int m = 0; m < 4; ++m) {
#pragma unroll
    for (int n = 0; n < 4; ++n) {
      int row = row0 + wr + m * 16 + ((lane >> 4) << 2);
      int col = col0 + wc + n * 16 + (lane & 15);
      float bcol = bias ? bias[col] : 0.f;
#pragma unroll
      for (int r = 0; r < 4; ++r) {
        int rr = row + r;
        if (rr < M) {
          float v = acc[m][n][r] + bcol;
          if (act) v = 0.5f * v * (1.0f + erff(v * 0.70710678118f)); // exact gelu
          if (res) v += res[(size_t)rr * N + col];
          if (Cf) Cf[(size_t)rr * N + col] = v;
          if (Ch) Ch[(size_t)rr * N + col] = (_Float16)v;
        }
      }
    }
  }
}

// ---------------- weight convert + transpose: W[K][N] f32 -> Wt[N][K] fp16 ----------------
__global__ __launch_bounds__(256) void cvt_wt(
    const float* __restrict__ W, _Float16* __restrict__ Wt, int K, int N)
{
  __shared__ float t[32][33];
  int k0 = blockIdx.y * 32, n0 = blockIdx.x * 32;
  int tx = threadIdx.x & 31, ty = threadIdx.x >> 5;   // 8 rows per pass
#pragma unroll
  for (int r = ty; r < 32; r += 8) t[r][tx] = W[(size_t)(k0 + r) * N + n0 + tx];
  __syncthreads();
#pragma unroll
  for (int r = ty; r < 32; r += 8) Wt[(size_t)(n0 + r) * K + k0 + tx] = (_Float16)t[tx][r];
}

// ---------------- LayerNorm over 512, one wave per row; f32 in, fp16 out ----------------
__global__ __launch_bounds__(64) void layernorm512(
    const float* __restrict__ in, _Float16* __restrict__ out,
    const float* __restrict__ g, const float* __restrict__ bb)
{
  int row = blockIdx.x;
  int t = threadIdx.x;
  const float* x = in + (size_t)row * DIM;
  float xa[8];
  *(float4*)(xa)     = *(const float4*)(x + t * 4);
  *(float4*)(xa + 4) = *(const float4*)(x + 256 + t * 4);
  float s = 0.f, sq = 0.f;
#pragma unroll
  for (int i = 0; i < 8; ++i) { s += xa[i]; sq += xa[i] * xa[i]; }
#pragma unroll
  for (int off = 32; off; off >>= 1) { s += __shfl_xor(s, off); sq += __shfl_xor(sq, off); }
  float mean = s * (1.f / 512.f);
  float var = sq * (1.f / 512.f) - mean * mean;
  float rs = rsqrtf(var + 1e-5f);
  float ga[8], ba[8];
  *(float4*)(ga)     = *(const float4*)(g + t * 4);
  *(float4*)(ga + 4) = *(const float4*)(g + 256 + t * 4);
  *(float4*)(ba)     = *(const float4*)(bb + t * 4);
  *(float4*)(ba + 4) = *(const float4*)(bb + 256 + t * 4);
  f16x4 o0, o1;
#pragma unroll
  for (int i = 0; i < 4; ++i) o0[i] = (_Float16)((xa[i] - mean) * rs * ga[i] + ba[i]);
#pragma unroll
  for (int i = 0; i < 4; ++i) o1[i] = (_Float16)((xa[i + 4] - mean) * rs * ga[i + 4] + ba[i + 4]);
  _Float16* y = out + (size_t)row * DIM;
  *(f16x4*)(y + t * 4)       = o0;
  *(f16x4*)(y + 256 + t * 4) = o1;
}

// ---------------- Embedding: tokens[r] = tok_emb[ids[r]] + dp_pos[r%4] ----------------
__global__ __launch_bounds__(128) void embed_tokens(
    const int* __restrict__ ids, const float* __restrict__ tok_emb,
    const float* __restrict__ dp_pos, float* __restrict__ tokens)
{
  int r = blockIdx.x;
  int dpt = r & 3;
  int id = ids[r];
  int c = threadIdx.x * 4;
  float4 e = *(const float4*)(tok_emb + (size_t)id * 512 + c);
  float4 p = *(const float4*)(dp_pos + dpt * 512 + c);
  float4 o = make_float4(e.x + p.x, e.y + p.y, e.z + p.z, e.w + p.w);
  *(float4*)(tokens + (size_t)r * 512 + c) = o;
}

// ---------------- spatial input rows ----------------
__global__ __launch_bounds__(128) void spatial_init(
    const float* __restrict__ tokens, const float* __restrict__ sp_pos,
    const float* __restrict__ start_tok, float* __restrict__ x_sp)
{
  int r = blockIdx.x;
  int b = r / NSP, s = r % NSP;
  int c = threadIdx.x * 4;
  float4 o;
  if (s == 0) {
    o = *(const float4*)(start_tok + c);
  } else {
    int s0 = s - 1;
    const float* tb = tokens + ((size_t)(b * 512 + s0) * 4) * 512 + c;
    float4 t0 = *(const float4*)(tb);
    float4 t1 = *(const float4*)(tb + 512);
    float4 t2 = *(const float4*)(tb + 1024);
    float4 t3 = *(const float4*)(tb + 1536);
    float4 pp = *(const float4*)(sp_pos + (size_t)s0 * 512 + c);
    o = make_float4(t0.x + t1.x + t2.x + t3.x + pp.x,
                    t0.y + t1.y + t2.y + t3.y + pp.y,
                    t0.z + t1.z + t2.z + t3.z + pp.z,
                    t0.w + t1.w + t2.w + t3.w + pp.w);
  }
  *(float4*)(x_sp + (size_t)r * 512 + c) = o;
}

// ---------------- spatial attention: scores+softmax into P ----------------
__global__ __launch_bounds__(256) void attn_sp_scores(
    const float* __restrict__ qkv, float* __restrict__ P)
{
  int i = blockIdx.x;
  int bh = blockIdx.y;
  int b = bh >> 3, h = bh & 7;
  int tid = threadIdx.x;
  __shared__ float q[64];
  __shared__ float red[256];
  const float* qrow = qkv + (size_t)(b * NSP + i) * 1536 + h * 64;
  if (tid < 64) q[tid] = qrow[tid] * 0.125f;
  __syncthreads();
  float sc[3];
  float mymax = -3.0e38f;
#pragma unroll
  for (int jj = 0; jj < 3; ++jj) {
    int j = tid + jj * 256;
    float sv = -3.0e38f;
    if (j <= i) {
      const float* krow = qkv + (size_t)(b * NSP + j) * 1536 + 512 + h * 64;
      float acc = 0.f;
#pragma unroll
      for (int d4 = 0; d4 < 16; ++d4) {
        float4 kv = *(const float4*)(krow + d4 * 4);
        float4 qv = *(const float4*)(&q[d4 * 4]);
        acc += qv.x * kv.x + qv.y * kv.y + qv.z * kv.z + qv.w * kv.w;
      }
      sv = acc;
      mymax = fmaxf(mymax, sv);
    }
    sc[jj] = sv;
  }
  red[tid] = mymax; __syncthreads();
  for (int st = 128; st > 0; st >>= 1) { if (tid < st) red[tid] = fmaxf(red[tid], red[tid + st]); __syncthreads(); }
  float bmax = red[0]; __syncthreads();
  float mysum = 0.f;
#pragma unroll
  for (int jj = 0; jj < 3; ++jj) {
    int j = tid + jj * 256;
    if (j <= i) { sc[jj] = expf(sc[jj] - bmax); mysum += sc[jj]; }
    else sc[jj] = 0.f;
  }
  red[tid] = mysum; __syncthreads();
  for (int st = 128; st > 0; st >>= 1) { if (tid < st) red[tid] += red[tid + st]; __syncthreads(); }
  float inv = 1.0f / red[0];
  float* prow = P + ((size_t)bh * NSP + i) * NSP;
#pragma unroll
  for (int jj = 0; jj < 3; ++jj) {
    int j = tid + jj * 256;
    if (j < NSP) prow[j] = (j <= i) ? sc[jj] * inv : 0.f;
  }
}

// ---------------- spatial attention: O = P @ V (fp16 out) ----------------
__global__ __launch_bounds__(256) void attn_sp_pv(
    const float* __restrict__ qkv, const float* __restrict__ P, _Float16* __restrict__ O)
{
  int row = blockIdx.x;
  int b = row / NSP, i = row % NSP;
  int tid = threadIdx.x;
#pragma unroll
  for (int cc = 0; cc < 2; ++cc) {
    int c = tid + cc * 256;
    int h = c >> 6, d = c & 63;
    const float* prow = P + ((size_t)(b * 8 + h) * NSP + i) * NSP;
    const float* vbase = qkv + (size_t)(b * NSP) * 1536 + 1024 + h * 64 + d;
    float acc = 0.f;
    for (int j = 0; j <= i; ++j) acc = fmaf(prow[j], vbase[(size_t)j * 1536], acc);
    O[(size_t)row * 512 + c] = (_Float16)acc;
  }
}

// ---------------- depth attention (N=5), one wave per (r,h); fp16 out ----------------
__global__ __launch_bounds__(64) void attn_dp(
    const float* __restrict__ qkv, _Float16* __restrict__ O)
{
  int r = blockIdx.x;
  int h = blockIdx.y;
  int d = threadIdx.x;
  const float* base = qkv + (size_t)r * 5 * 1536 + h * 64 + d;
  float q[5], k[5], v[5];
#pragma unroll
  for (int p = 0; p < 5; ++p) {
    q[p] = base[p * 1536] * 0.125f;
    k[p] = base[p * 1536 + 512];
    v[p] = base[p * 1536 + 1024];
  }
#pragma unroll
  for (int i = 0; i < 5; ++i) {
    float s[5];
    float mx = -3.0e38f;
    for (int j = 0; j <= i; ++j) {
      float part = q[i] * k[j];
#pragma unroll
      for (int off = 32; off; off >>= 1) part += __shfl_xor(part, off);
      s[j] = part;
      mx = fmaxf(mx, part);
    }
    float sum = 0.f;
    for (int j = 0; j <= i; ++j) { s[j] = expf(s[j] - mx); sum += s[j]; }
    float invs = 1.0f / sum;
    float o = 0.f;
    for (int j = 0; j <= i; ++j) o += s[j] * v[j];
    O[((size_t)r * 5 + i) * 512 + h * 64 + d] = (_Float16)(o * invs);
  }
}

// ---------------- build depth-transformer input (fp16 sp_final + f32 tokens -> f32) ----------------
__global__ __launch_bounds__(128) void build_dt(
    const _Float16* __restrict__ sp_final, const float* __restrict__ tokens,
    float* __restrict__ x_dp)
{
  int row = blockIdx.x;
  int r = row / 5, cpos = row % 5;
  int c = threadIdx.x * 4;
  float4 o = make_float4(0.f, 0.f, 0.f, 0.f);
  if (cpos == 0) {
    f16x4 hv = *(const f16x4*)(sp_final + (size_t)r * 512 + c);
    o = make_float4((float)hv[0], (float)hv[1], (float)hv[2], (float)hv[3]);
  } else {
    int b = r / NSP, sp = r % NSP;
    if (sp < 512)
      o = *(const float4*)(tokens + ((size_t)((b * 512 + sp) * 4 + (cpos - 1))) * 512 + c);
  }
  *(float4*)(x_dp + (size_t)row * 512 + c) = o;
}

// ---------------- gather rows needed for logits (fp16 -> fp16) ----------------
__global__ __launch_bounds__(128) void gather_rows(
    const _Float16* __restrict__ xn, _Float16* __restrict__ dtg)
{
  int m = blockIdx.x;
  int b = m >> 11;
  int t = 1 + (m & 2047);
  int c = threadIdx.x * 4;
  *(f16x4*)(dtg + (size_t)m * 512 + c) =
      *(const f16x4*)(xn + ((size_t)b * 2565 + t) * 512 + c);
}

extern "C" void kernel_launch(void* const* d_in, const int* in_sizes, int n_in,
                              void* d_out, int out_size, void* d_ws, size_t ws_size,
                              hipStream_t stream)
{
  const int*   ids       = (const int*)  d_in[0];
  const float* tok_emb   = (const float*)d_in[1];
  const float* start_tok = (const float*)d_in[2];
  const float* sp_pos    = (const float*)d_in[3];
  const float* dp_pos    = (const float*)d_in[4];
  const float* w_logit   = (const float*)d_in[5];
  const float* b_logit   = (const float*)d_in[6];
  const float* sp_ln1g = (const float*)d_in[7];
  const float* sp_ln1b = (const float*)d_in[8];
  const float* sp_qkv  = (const float*)d_in[9];
  const float* sp_wo   = (const float*)d_in[10];
  const float* sp_ln2g = (const float*)d_in[11];
  const float* sp_ln2b = (const float*)d_in[12];
  const float* sp_w1   = (const float*)d_in[13];
  const float* sp_b1   = (const float*)d_in[14];
  const float* sp_w2   = (const float*)d_in[15];
  const float* sp_b2   = (const float*)d_in[16];
  const float* sp_lnfg = (const float*)d_in[17];
  const float* sp_lnfb = (const float*)d_in[18];
  const float* dp_ln1g = (const float*)d_in[19];
  const float* dp_ln1b = (const float*)d_in[20];
  const float* dp_qkv  = (const float*)d_in[21];
  const float* dp_wo   = (const float*)d_in[22];
  const float* dp_ln2g = (const float*)d_in[23];
  const float* dp_ln2b = (const float*)d_in[24];
  const float* dp_w1   = (const float*)d_in[25];
  const float* dp_b1   = (const float*)d_in[26];
  const float* dp_w2   = (const float*)d_in[27];
  const float* dp_b2   = (const float*)d_in[28];
  const float* dp_lnfg = (const float*)d_in[29];
  const float* dp_lnfb = (const float*)d_in[30];

  char* wsb = (char*)d_ws;
  size_t off = 0;
  auto alloc = [&](size_t bytes) { char* p = wsb + off; off += (bytes + 255) & ~(size_t)255; return p; };

  float* tokens = (float*)alloc((size_t)4096 * 512 * 4);
  float* x_sp   = (float*)alloc((size_t)SP_ROWS * 512 * 4);
  float* x_dp   = (float*)alloc((size_t)DP_ROWS * 512 * 4);
  float* qkvb   = (float*)alloc((size_t)DP_ROWS * 1536 * 4);
  _Float16* xnh    = (_Float16*)alloc((size_t)DP_ROWS * 512 * 2);
  _Float16* attnoh = (_Float16*)alloc((size_t)DP_ROWS * 512 * 2);
  char* ffP = alloc((size_t)DP_ROWS * 2048 * 2);     // ffh (fp16) and P (f32) alias: disjoint lifetimes
  _Float16* ffh = (_Float16*)ffP;
  float* P = (float*)ffP;                            // needs 16*513*513*4 = 16.8MB <= 21MB
  _Float16* dtgh = (_Float16*)alloc((size_t)OUT_ROWS * 512 * 2);
  // fp16 transposed weights
  _Float16* wt_sp_qkv = (_Float16*)alloc((size_t)4 * 1536 * 512 * 2);
  _Float16* wt_sp_wo  = (_Float16*)alloc((size_t)4 * 512 * 512 * 2);
  _Float16* wt_sp_w1  = (_Float16*)alloc((size_t)4 * 2048 * 512 * 2);
  _Float16* wt_sp_w2  = (_Float16*)alloc((size_t)4 * 512 * 2048 * 2);
  _Float16* wt_dp_qkv = (_Float16*)alloc((size_t)2 * 1536 * 512 * 2);
  _Float16* wt_dp_wo  = (_Float16*)alloc((size_t)2 * 512 * 512 * 2);
  _Float16* wt_dp_w1  = (_Float16*)alloc((size_t)2 * 2048 * 512 * 2);
  _Float16* wt_dp_w2  = (_Float16*)alloc((size_t)2 * 512 * 2048 * 2);
  _Float16* wt_logit  = (_Float16*)alloc((size_t)16384 * 512 * 2);

  auto cvt = [&](const float* W, _Float16* Wt, int L, int K, int N) {
    for (int l = 0; l < L; ++l)
      cvt_wt<<<dim3(N / 32, K / 32), 256, 0, stream>>>(W + (size_t)l * K * N, Wt + (size_t)l * N * K, K, N);
  };
  cvt(sp_qkv, wt_sp_qkv, 4, 512, 1536);
  cvt(sp_wo,  wt_sp_wo,  4, 512, 512);
  cvt(sp_w1,  wt_sp_w1,  4, 512, 2048);
  cvt(sp_w2,  wt_sp_w2,  4, 2048, 512);
  cvt(dp_qkv, wt_dp_qkv, 2, 512, 1536);
  cvt(dp_wo,  wt_dp_wo,  2, 512, 512);
  cvt(dp_w1,  wt_dp_w1,  2, 512, 2048);
  cvt(dp_w2,  wt_dp_w2,  2, 2048, 512);
  cvt(w_logit, wt_logit, 1, 512, 16384);

  auto gemm = [&](const _Float16* A, const _Float16* Bt, const float* bias, const float* res,
                  float* Cf, _Float16* Ch, int M, int N, int K, int act) {
    dim3 g(N / 128, (M + 127) / 128);
    gemm_h<<<g, 256, 0, stream>>>(A, Bt, bias, res, Cf, Ch, M, N, K, act);
  };

  embed_tokens<<<4096, 128, 0, stream>>>(ids, tok_emb, dp_pos, tokens);
  spatial_init<<<SP_ROWS, 128, 0, stream>>>(tokens, sp_pos, start_tok, x_sp);

  for (int l = 0; l < 4; ++l) {
    layernorm512<<<SP_ROWS, 64, 0, stream>>>(x_sp, xnh, sp_ln1g + l * 512, sp_ln1b + l * 512);
    gemm(xnh, wt_sp_qkv + (size_t)l * 1536 * 512, nullptr, nullptr, qkvb, nullptr, SP_ROWS, 1536, 512, 0);
    attn_sp_scores<<<dim3(NSP, 16), 256, 0, stream>>>(qkvb, P);
    attn_sp_pv<<<SP_ROWS, 256, 0, stream>>>(qkvb, P, attnoh);
    gemm(attnoh, wt_sp_wo + (size_t)l * 512 * 512, nullptr, x_sp, x_sp, nullptr, SP_ROWS, 512, 512, 0);
    layernorm512<<<SP_ROWS, 64, 0, stream>>>(x_sp, xnh, sp_ln2g + l * 512, sp_ln2b + l * 512);
    gemm(xnh, wt_sp_w1 + (size_t)l * 2048 * 512, sp_b1 + l * 2048, nullptr, nullptr, ffh, SP_ROWS, 2048, 512, 1);
    gemm(ffh, wt_sp_w2 + (size_t)l * 512 * 2048, sp_b2 + l * 512, x_sp, x_sp, nullptr, SP_ROWS, 512, 2048, 0);
  }
  layernorm512<<<SP_ROWS, 64, 0, stream>>>(x_sp, xnh, sp_lnfg, sp_lnfb);
  build_dt<<<DP_ROWS, 128, 0, stream>>>(xnh, tokens, x_dp);

  for (int l = 0; l < 2; ++l) {
    layernorm512<<<DP_ROWS, 64, 0, stream>>>(x_dp, xnh, dp_ln1g + l * 512, dp_ln1b + l * 512);
    gemm(xnh, wt_dp_qkv + (size_t)l * 1536 * 512, nullptr, nullptr, qkvb, nullptr, DP_ROWS, 1536, 512, 0);
    attn_dp<<<dim3(SP_ROWS, 8), 64, 0, stream>>>(qkvb, attnoh);
    gemm(attnoh, wt_dp_wo + (size_t)l * 512 * 512, nullptr, x_dp, x_dp, nullptr, DP_ROWS, 512, 512, 0);
    layernorm512<<<DP_ROWS, 64, 0, stream>>>(x_dp, xnh, dp_ln2g + l * 512, dp_ln2b + l * 512);
    gemm(xnh, wt_dp_w1 + (size_t)l * 2048 * 512, dp_b1 + l * 2048, nullptr, nullptr, ffh, DP_ROWS, 2048, 512, 1);
    gemm(ffh, wt_dp_w2 + (size_t)l * 512 * 2048, dp_b2 + l * 512, x_dp, x_dp, nullptr, DP_ROWS, 512, 2048, 0);
  }
  layernorm512<<<DP_ROWS, 64, 0, stream>>>(x_dp, xnh, dp_lnfg, dp_lnfb);
  gather_rows<<<OUT_ROWS, 128, 0, stream>>>(xnh, dtgh);
  gemm(dtgh, wt_logit, b_logit, nullptr, (float*)d_out, nullptr, OUT_ROWS, VOCABN, 512, 0);
}

// Round 3
// 1649.681 us; speedup vs baseline: 3.9389x; 1.5799x over previous
//
#include <hip/hip_runtime.h>
#include <math.h>

#define DIM 512
#define NSP 513                 // spatial seq len (MAX_S+1)
#define BATCHB 2
#define SP_ROWS (BATCHB*NSP)    // 1026
#define DP_ROWS (SP_ROWS*5)     // 5130
#define OUT_ROWS (BATCHB*2048)  // 4096
#define VOCABN 16384

typedef _Float16 f16x8 __attribute__((ext_vector_type(8)));
typedef _Float16 f16x4 __attribute__((ext_vector_type(4)));
typedef float    f32x4 __attribute__((ext_vector_type(4)));

#define LDK 40   // 32 + 8 fp16 pad (16B) -> 80B row stride in LDS

// ---------------- fp16 MFMA GEMM: C = act(A@B^T' + bias) + res ----------------
// A[M][K] fp16 row-major, Bt[N][K] fp16 row-major (weights pre-transposed).
// 128x128 tile, BK=32, 256 threads = 4 waves, each wave 64x64 (4x4 16x16x32 frags).
__global__ __launch_bounds__(256) void gemm_h(
    const _Float16* __restrict__ A, const _Float16* __restrict__ Bt,
    const float* __restrict__ bias, const float* __restrict__ res,
    float* __restrict__ Cf, _Float16* __restrict__ Ch,
    int M, int N, int K, int act)
{
  __shared__ __align__(16) _Float16 As[128 * LDK];
  __shared__ __align__(16) _Float16 Bs[128 * LDK];
  int tid = threadIdx.x;
  int wid = tid >> 6, lane = tid & 63;
  int row0 = blockIdx.y * 128, col0 = blockIdx.x * 128;
  int wr = (wid >> 1) * 64, wc = (wid & 1) * 64;

  int ar = tid >> 1;
  int kh = (tid & 1) * 16;
  int arow = row0 + ar; if (arow > M - 1) arow = M - 1;
  bool aval = (row0 + ar) < M;
  const _Float16* Ap = A + (size_t)arow * K + kh;
  const _Float16* Bp = Bt + (size_t)(col0 + ar) * K + kh;

  f16x8 za;
#pragma unroll
  for (int i = 0; i < 8; ++i) za[i] = (_Float16)0.f;
  f32x4 acc[4][4];
#pragma unroll
  for (int m = 0; m < 4; ++m)
#pragma unroll
    for (int n = 0; n < 4; ++n) acc[m][n] = 0.f;

  const int nt = K >> 5;
  f16x8 ra0 = aval ? *(const f16x8*)(Ap) : za;
  f16x8 ra1 = aval ? *(const f16x8*)(Ap + 8) : za;
  f16x8 rb0 = *(const f16x8*)(Bp);
  f16x8 rb1 = *(const f16x8*)(Bp + 8);

  for (int t = 0; t < nt; ++t) {
    *(f16x8*)(&As[ar * LDK + kh])     = ra0;
    *(f16x8*)(&As[ar * LDK + kh + 8]) = ra1;
    *(f16x8*)(&Bs[ar * LDK + kh])     = rb0;
    *(f16x8*)(&Bs[ar * LDK + kh + 8]) = rb1;
    __syncthreads();
    if (t + 1 < nt) {
      const _Float16* Ap2 = Ap + (t + 1) * 32;
      const _Float16* Bp2 = Bp + (t + 1) * 32;
      ra0 = aval ? *(const f16x8*)(Ap2) : za;
      ra1 = aval ? *(const f16x8*)(Ap2 + 8) : za;
      rb0 = *(const f16x8*)(Bp2);
      rb1 = *(const f16x8*)(Bp2 + 8);
    }
    f16x8 af[4], bf[4];
#pragma unroll
    for (int m = 0; m < 4; ++m)
      af[m] = *(const f16x8*)(&As[(wr + m * 16 + (lane & 15)) * LDK + ((lane >> 4) << 3)]);
#pragma unroll
    for (int n = 0; n < 4; ++n)
      bf[n] = *(const f16x8*)(&Bs[(wc + n * 16 + (lane & 15)) * LDK + ((lane >> 4) << 3)]);
#pragma unroll
    for (int m = 0; m < 4; ++m)
#pragma unroll
      for (int n = 0; n < 4; ++n)
        acc[m][n] = __builtin_amdgcn_mfma_f32_16x16x32_f16(af[m], bf[n], acc[m][n], 0, 0, 0);
    __syncthreads();
  }

#pragma unroll
  for (int m = 0; m < 4; ++m) {
#pragma unroll
    for (int n = 0; n < 4; ++n) {
      int row = row0 + wr + m * 16 + ((lane >> 4) << 2);
      int col = col0 + wc + n * 16 + (lane & 15);
      float bcol = bias ? bias[col] : 0.f;
#pragma unroll
      for (int r = 0; r < 4; ++r) {
        int rr = row + r;
        if (rr < M) {
          float v = acc[m][n][r] + bcol;
          if (act) v = 0.5f * v * (1.0f + erff(v * 0.70710678118f)); // exact gelu
          if (res) v += res[(size_t)rr * N + col];
          if (Cf) Cf[(size_t)rr * N + col] = v;
          if (Ch) Ch[(size_t)rr * N + col] = (_Float16)v;
        }
      }
    }
  }
}

// ---------------- fused causal flash attention (spatial), fp16 QKV ----------------
// qkv[SP_ROWS][1536] fp16 (q|k|v per head h: h*64). O[SP_ROWS][512] fp16.
// Block: (qtile, bh). 256 thr = 4 waves, each wave 16 q-rows. kv tiles of 64.
#define LDSK2 72
#define LDSV2 72
#define LDSP2 18
__global__ __launch_bounds__(256) void flash_sp(
    const _Float16* __restrict__ qkv, _Float16* __restrict__ O)
{
  __shared__ __align__(16) _Float16 K_lds[64 * LDSK2];
  __shared__ __align__(16) _Float16 V_lds[64 * LDSV2];   // transposed: [d][kv]
  __shared__ __align__(16) _Float16 P_lds[4][64 * LDSP2]; // per-wave [kv][q]
  int qt = blockIdx.x;       // 0..8
  int bh = blockIdx.y;       // b*8+h
  int b = bh >> 3, h = bh & 7;
  int tid = threadIdx.x, wid = tid >> 6, lane = tid & 63;
  int lq = lane & 15, lg = lane >> 4;
  int q0 = qt * 64 + wid * 16;
  int qg = q0 + lq;                       // this lane's q column (global)
  int qrow = b * NSP + (qg < NSP ? qg : NSP - 1);

  f16x8 Qf[2];
#pragma unroll
  for (int s = 0; s < 2; ++s) {
    Qf[s] = *(const f16x8*)(qkv + (size_t)qrow * 1536 + h * 64 + s * 32 + lg * 8);
#pragma unroll
    for (int i = 0; i < 8; ++i) Qf[s][i] = Qf[s][i] * (_Float16)0.125f;  // 1/sqrt(64)
  }

  float m = -3.0e38f, l = 0.f;
  f32x4 oacc[4];
#pragma unroll
  for (int n = 0; n < 4; ++n) oacc[n] = 0.f;

  int ntile = qt + 1;
  for (int t = 0; t < ntile; ++t) {
    int kv0 = t * 64;
#pragma unroll
    for (int j = 0; j < 2; ++j) {
      int idx = tid + j * 256;
      int row = idx >> 3, dc = (idx & 7) * 8;
      int kvr = kv0 + row;
      int grow = b * NSP + (kvr < NSP ? kvr : NSP - 1);
      f16x8 k8 = *(const f16x8*)(qkv + (size_t)grow * 1536 + 512 + h * 64 + dc);
      *(f16x8*)(&K_lds[row * LDSK2 + dc]) = k8;
      f16x8 v8 = *(const f16x8*)(qkv + (size_t)grow * 1536 + 1024 + h * 64 + dc);
#pragma unroll
      for (int e = 0; e < 8; ++e) V_lds[(dc + e) * LDSV2 + row] = v8[e];
    }
    __syncthreads();
    // S^T = K @ Q^T
    f32x4 st[4];
#pragma unroll
    for (int f = 0; f < 4; ++f) st[f] = 0.f;
#pragma unroll
    for (int s = 0; s < 2; ++s)
#pragma unroll
      for (int f = 0; f < 4; ++f) {
        f16x8 kf = *(const f16x8*)(&K_lds[(f * 16 + lq) * LDSK2 + s * 32 + lg * 8]);
        st[f] = __builtin_amdgcn_mfma_f32_16x16x32_f16(kf, Qf[s], st[f], 0, 0, 0);
      }
    // mask + online softmax (stats uniform per lane: q = lq)
    float tmax = -3.0e38f;
#pragma unroll
    for (int f = 0; f < 4; ++f)
#pragma unroll
      for (int r = 0; r < 4; ++r) {
        int kvg = kv0 + f * 16 + lg * 4 + r;
        bool ok = (kvg <= qg) && (qg < NSP);
        if (ok) tmax = fmaxf(tmax, st[f][r]);
      }
    tmax = fmaxf(tmax, __shfl_xor(tmax, 16));
    tmax = fmaxf(tmax, __shfl_xor(tmax, 32));
    float mnew = fmaxf(m, tmax);
    float scale = __expf(m - mnew);
    float tsum = 0.f;
#pragma unroll
    for (int f = 0; f < 4; ++f)
#pragma unroll
      for (int r = 0; r < 4; ++r) {
        int kvg = kv0 + f * 16 + lg * 4 + r;
        bool ok = (kvg <= qg) && (qg < NSP);
        float p = ok ? __expf(st[f][r] - mnew) : 0.f;
        tsum += p;
        P_lds[wid][(f * 16 + lg * 4 + r) * LDSP2 + lq] = (_Float16)p;
      }
    tsum += __shfl_xor(tsum, 16);
    tsum += __shfl_xor(tsum, 32);
    l = l * scale + tsum;
    m = mnew;
#pragma unroll
    for (int n = 0; n < 4; ++n)
#pragma unroll
      for (int r = 0; r < 4; ++r) oacc[n][r] *= scale;
    // O^T += V^T @ P^T
#pragma unroll
    for (int s = 0; s < 2; ++s) {
      f16x8 pf;
#pragma unroll
      for (int i = 0; i < 8; ++i) pf[i] = P_lds[wid][(s * 32 + lg * 8 + i) * LDSP2 + lq];
#pragma unroll
      for (int n = 0; n < 4; ++n) {
        f16x8 vf = *(const f16x8*)(&V_lds[(n * 16 + lq) * LDSV2 + s * 32 + lg * 8]);
        oacc[n] = __builtin_amdgcn_mfma_f32_16x16x32_f16(vf, pf, oacc[n], 0, 0, 0);
      }
    }
    __syncthreads();
  }
  if (qg < NSP) {
    float invl = 1.0f / l;
    _Float16* orow = O + (size_t)(b * NSP + qg) * 512 + h * 64;
#pragma unroll
    for (int n = 0; n < 4; ++n)
#pragma unroll
      for (int r = 0; r < 4; ++r)
        orow[n * 16 + lg * 4 + r] = (_Float16)(oacc[n][r] * invl);
  }
}

// ---------------- weight convert + transpose: W[K][N] f32 -> Wt[N][K] fp16 ----------------
__global__ __launch_bounds__(256) void cvt_wt(
    const float* __restrict__ W, _Float16* __restrict__ Wt, int K, int N)
{
  __shared__ float t[32][33];
  int k0 = blockIdx.y * 32, n0 = blockIdx.x * 32;
  int tx = threadIdx.x & 31, ty = threadIdx.x >> 5;
#pragma unroll
  for (int r = ty; r < 32; r += 8) t[r][tx] = W[(size_t)(k0 + r) * N + n0 + tx];
  __syncthreads();
#pragma unroll
  for (int r = ty; r < 32; r += 8) Wt[(size_t)(n0 + r) * K + k0 + tx] = (_Float16)t[tx][r];
}

// ---------------- LayerNorm over 512, one wave per row; f32 in, fp16 out ----------------
__global__ __launch_bounds__(64) void layernorm512(
    const float* __restrict__ in, _Float16* __restrict__ out,
    const float* __restrict__ g, const float* __restrict__ bb)
{
  int row = blockIdx.x;
  int t = threadIdx.x;
  const float* x = in + (size_t)row * DIM;
  float xa[8];
  *(float4*)(xa)     = *(const float4*)(x + t * 4);
  *(float4*)(xa + 4) = *(const float4*)(x + 256 + t * 4);
  float s = 0.f, sq = 0.f;
#pragma unroll
  for (int i = 0; i < 8; ++i) { s += xa[i]; sq += xa[i] * xa[i]; }
#pragma unroll
  for (int off = 32; off; off >>= 1) { s += __shfl_xor(s, off); sq += __shfl_xor(sq, off); }
  float mean = s * (1.f / 512.f);
  float var = sq * (1.f / 512.f) - mean * mean;
  float rs = rsqrtf(var + 1e-5f);
  float ga[8], ba[8];
  *(float4*)(ga)     = *(const float4*)(g + t * 4);
  *(float4*)(ga + 4) = *(const float4*)(g + 256 + t * 4);
  *(float4*)(ba)     = *(const float4*)(bb + t * 4);
  *(float4*)(ba + 4) = *(const float4*)(bb + 256 + t * 4);
  f16x4 o0, o1;
#pragma unroll
  for (int i = 0; i < 4; ++i) o0[i] = (_Float16)((xa[i] - mean) * rs * ga[i] + ba[i]);
#pragma unroll
  for (int i = 0; i < 4; ++i) o1[i] = (_Float16)((xa[i + 4] - mean) * rs * ga[i + 4] + ba[i + 4]);
  _Float16* y = out + (size_t)row * DIM;
  *(f16x4*)(y + t * 4)       = o0;
  *(f16x4*)(y + 256 + t * 4) = o1;
}

// ---------------- Embedding ----------------
__global__ __launch_bounds__(128) void embed_tokens(
    const int* __restrict__ ids, const float* __restrict__ tok_emb,
    const float* __restrict__ dp_pos, float* __restrict__ tokens)
{
  int r = blockIdx.x;
  int dpt = r & 3;
  int id = ids[r];
  int c = threadIdx.x * 4;
  float4 e = *(const float4*)(tok_emb + (size_t)id * 512 + c);
  float4 p = *(const float4*)(dp_pos + dpt * 512 + c);
  float4 o = make_float4(e.x + p.x, e.y + p.y, e.z + p.z, e.w + p.w);
  *(float4*)(tokens + (size_t)r * 512 + c) = o;
}

// ---------------- spatial input rows ----------------
__global__ __launch_bounds__(128) void spatial_init(
    const float* __restrict__ tokens, const float* __restrict__ sp_pos,
    const float* __restrict__ start_tok, float* __restrict__ x_sp)
{
  int r = blockIdx.x;
  int b = r / NSP, s = r % NSP;
  int c = threadIdx.x * 4;
  float4 o;
  if (s == 0) {
    o = *(const float4*)(start_tok + c);
  } else {
    int s0 = s - 1;
    const float* tb = tokens + ((size_t)(b * 512 + s0) * 4) * 512 + c;
    float4 t0 = *(const float4*)(tb);
    float4 t1 = *(const float4*)(tb + 512);
    float4 t2 = *(const float4*)(tb + 1024);
    float4 t3 = *(const float4*)(tb + 1536);
    float4 pp = *(const float4*)(sp_pos + (size_t)s0 * 512 + c);
    o = make_float4(t0.x + t1.x + t2.x + t3.x + pp.x,
                    t0.y + t1.y + t2.y + t3.y + pp.y,
                    t0.z + t1.z + t2.z + t3.z + pp.z,
                    t0.w + t1.w + t2.w + t3.w + pp.w);
  }
  *(float4*)(x_sp + (size_t)r * 512 + c) = o;
}

// ---------------- depth attention (N=5), one wave per (r,h); fp16 in/out ----------------
__global__ __launch_bounds__(64) void attn_dp(
    const _Float16* __restrict__ qkv, _Float16* __restrict__ O)
{
  int r = blockIdx.x;
  int h = blockIdx.y;
  int d = threadIdx.x;
  const _Float16* base = qkv + (size_t)r * 5 * 1536 + h * 64 + d;
  float q[5], k[5], v[5];
#pragma unroll
  for (int p = 0; p < 5; ++p) {
    q[p] = (float)base[p * 1536] * 0.125f;
    k[p] = (float)base[p * 1536 + 512];
    v[p] = (float)base[p * 1536 + 1024];
  }
#pragma unroll
  for (int i = 0; i < 5; ++i) {
    float s[5];
    float mx = -3.0e38f;
    for (int j = 0; j <= i; ++j) {
      float part = q[i] * k[j];
#pragma unroll
      for (int off = 32; off; off >>= 1) part += __shfl_xor(part, off);
      s[j] = part;
      mx = fmaxf(mx, part);
    }
    float sum = 0.f;
    for (int j = 0; j <= i; ++j) { s[j] = expf(s[j] - mx); sum += s[j]; }
    float invs = 1.0f / sum;
    float o = 0.f;
    for (int j = 0; j <= i; ++j) o += s[j] * v[j];
    O[((size_t)r * 5 + i) * 512 + h * 64 + d] = (_Float16)(o * invs);
  }
}

// ---------------- build depth-transformer input ----------------
__global__ __launch_bounds__(128) void build_dt(
    const _Float16* __restrict__ sp_final, const float* __restrict__ tokens,
    float* __restrict__ x_dp)
{
  int row = blockIdx.x;
  int r = row / 5, cpos = row % 5;
  int c = threadIdx.x * 4;
  float4 o = make_float4(0.f, 0.f, 0.f, 0.f);
  if (cpos == 0) {
    f16x4 hv = *(const f16x4*)(sp_final + (size_t)r * 512 + c);
    o = make_float4((float)hv[0], (float)hv[1], (float)hv[2], (float)hv[3]);
  } else {
    int b = r / NSP, sp = r % NSP;
    if (sp < 512)
      o = *(const float4*)(tokens + ((size_t)((b * 512 + sp) * 4 + (cpos - 1))) * 512 + c);
  }
  *(float4*)(x_dp + (size_t)row * 512 + c) = o;
}

// ---------------- gather rows needed for logits ----------------
__global__ __launch_bounds__(128) void gather_rows(
    const _Float16* __restrict__ xn, _Float16* __restrict__ dtg)
{
  int m = blockIdx.x;
  int b = m >> 11;
  int t = 1 + (m & 2047);
  int c = threadIdx.x * 4;
  *(f16x4*)(dtg + (size_t)m * 512 + c) =
      *(const f16x4*)(xn + ((size_t)b * 2565 + t) * 512 + c);
}

extern "C" void kernel_launch(void* const* d_in, const int* in_sizes, int n_in,
                              void* d_out, int out_size, void* d_ws, size_t ws_size,
                              hipStream_t stream)
{
  const int*   ids       = (const int*)  d_in[0];
  const float* tok_emb   = (const float*)d_in[1];
  const float* start_tok = (const float*)d_in[2];
  const float* sp_pos    = (const float*)d_in[3];
  const float* dp_pos    = (const float*)d_in[4];
  const float* w_logit   = (const float*)d_in[5];
  const float* b_logit   = (const float*)d_in[6];
  const float* sp_ln1g = (const float*)d_in[7];
  const float* sp_ln1b = (const float*)d_in[8];
  const float* sp_qkv  = (const float*)d_in[9];
  const float* sp_wo   = (const float*)d_in[10];
  const float* sp_ln2g = (const float*)d_in[11];
  const float* sp_ln2b = (const float*)d_in[12];
  const float* sp_w1   = (const float*)d_in[13];
  const float* sp_b1   = (const float*)d_in[14];
  const float* sp_w2   = (const float*)d_in[15];
  const float* sp_b2   = (const float*)d_in[16];
  const float* sp_lnfg = (const float*)d_in[17];
  const float* sp_lnfb = (const float*)d_in[18];
  const float* dp_ln1g = (const float*)d_in[19];
  const float* dp_ln1b = (const float*)d_in[20];
  const float* dp_qkv  = (const float*)d_in[21];
  const float* dp_wo   = (const float*)d_in[22];
  const float* dp_ln2g = (const float*)d_in[23];
  const float* dp_ln2b = (const float*)d_in[24];
  const float* dp_w1   = (const float*)d_in[25];
  const float* dp_b1   = (const float*)d_in[26];
  const float* dp_w2   = (const float*)d_in[27];
  const float* dp_b2   = (const float*)d_in[28];
  const float* dp_lnfg = (const float*)d_in[29];
  const float* dp_lnfb = (const float*)d_in[30];

  char* wsb = (char*)d_ws;
  size_t off = 0;
  auto alloc = [&](size_t bytes) { char* p = wsb + off; off += (bytes + 255) & ~(size_t)255; return p; };

  float* tokens = (float*)alloc((size_t)4096 * 512 * 4);
  float* x_sp   = (float*)alloc((size_t)SP_ROWS * 512 * 4);
  float* x_dp   = (float*)alloc((size_t)DP_ROWS * 512 * 4);
  _Float16* qkvh   = (_Float16*)alloc((size_t)DP_ROWS * 1536 * 2);
  _Float16* xnh    = (_Float16*)alloc((size_t)DP_ROWS * 512 * 2);
  _Float16* attnoh = (_Float16*)alloc((size_t)DP_ROWS * 512 * 2);
  _Float16* ffh    = (_Float16*)alloc((size_t)DP_ROWS * 2048 * 2);
  _Float16* dtgh   = (_Float16*)alloc((size_t)OUT_ROWS * 512 * 2);
  // fp16 transposed weights
  _Float16* wt_sp_qkv = (_Float16*)alloc((size_t)4 * 1536 * 512 * 2);
  _Float16* wt_sp_wo  = (_Float16*)alloc((size_t)4 * 512 * 512 * 2);
  _Float16* wt_sp_w1  = (_Float16*)alloc((size_t)4 * 2048 * 512 * 2);
  _Float16* wt_sp_w2  = (_Float16*)alloc((size_t)4 * 512 * 2048 * 2);
  _Float16* wt_dp_qkv = (_Float16*)alloc((size_t)2 * 1536 * 512 * 2);
  _Float16* wt_dp_wo  = (_Float16*)alloc((size_t)2 * 512 * 512 * 2);
  _Float16* wt_dp_w1  = (_Float16*)alloc((size_t)2 * 2048 * 512 * 2);
  _Float16* wt_dp_w2  = (_Float16*)alloc((size_t)2 * 512 * 2048 * 2);
  _Float16* wt_logit  = (_Float16*)alloc((size_t)16384 * 512 * 2);

  auto cvt = [&](const float* W, _Float16* Wt, int L, int K, int N) {
    for (int l = 0; l < L; ++l)
      cvt_wt<<<dim3(N / 32, K / 32), 256, 0, stream>>>(W + (size_t)l * K * N, Wt + (size_t)l * N * K, K, N);
  };
  cvt(sp_qkv, wt_sp_qkv, 4, 512, 1536);
  cvt(sp_wo,  wt_sp_wo,  4, 512, 512);
  cvt(sp_w1,  wt_sp_w1,  4, 512, 2048);
  cvt(sp_w2,  wt_sp_w2,  4, 2048, 512);
  cvt(dp_qkv, wt_dp_qkv, 2, 512, 1536);
  cvt(dp_wo,  wt_dp_wo,  2, 512, 512);
  cvt(dp_w1,  wt_dp_w1,  2, 512, 2048);
  cvt(dp_w2,  wt_dp_w2,  2, 2048, 512);
  cvt(w_logit, wt_logit, 1, 512, 16384);

  auto gemm = [&](const _Float16* A, const _Float16* Bt, const float* bias, const float* res,
                  float* Cf, _Float16* Ch, int M, int N, int K, int act) {
    dim3 g(N / 128, (M + 127) / 128);
    gemm_h<<<g, 256, 0, stream>>>(A, Bt, bias, res, Cf, Ch, M, N, K, act);
  };

  embed_tokens<<<4096, 128, 0, stream>>>(ids, tok_emb, dp_pos, tokens);
  spatial_init<<<SP_ROWS, 128, 0, stream>>>(tokens, sp_pos, start_tok, x_sp);

  for (int l = 0; l < 4; ++l) {
    layernorm512<<<SP_ROWS, 64, 0, stream>>>(x_sp, xnh, sp_ln1g + l * 512, sp_ln1b + l * 512);
    gemm(xnh, wt_sp_qkv + (size_t)l * 1536 * 512, nullptr, nullptr, nullptr, qkvh, SP_ROWS, 1536, 512, 0);
    flash_sp<<<dim3(9, 16), 256, 0, stream>>>(qkvh, attnoh);
    gemm(attnoh, wt_sp_wo + (size_t)l * 512 * 512, nullptr, x_sp, x_sp, nullptr, SP_ROWS, 512, 512, 0);
    layernorm512<<<SP_ROWS, 64, 0, stream>>>(x_sp, xnh, sp_ln2g + l * 512, sp_ln2b + l * 512);
    gemm(xnh, wt_sp_w1 + (size_t)l * 2048 * 512, sp_b1 + l * 2048, nullptr, nullptr, ffh, SP_ROWS, 2048, 512, 1);
    gemm(ffh, wt_sp_w2 + (size_t)l * 512 * 2048, sp_b2 + l * 512, x_sp, x_sp, nullptr, SP_ROWS, 512, 2048, 0);
  }
  layernorm512<<<SP_ROWS, 64, 0, stream>>>(x_sp, xnh, sp_lnfg, sp_lnfb);
  build_dt<<<DP_ROWS, 128, 0, stream>>>(xnh, tokens, x_dp);

  for (int l = 0; l < 2; ++l) {
    layernorm512<<<DP_ROWS, 64, 0, stream>>>(x_dp, xnh, dp_ln1g + l * 512, dp_ln1b + l * 512);
    gemm(xnh, wt_dp_qkv + (size_t)l * 1536 * 512, nullptr, nullptr, nullptr, qkvh, DP_ROWS, 1536, 512, 0);
    attn_dp<<<dim3(SP_ROWS, 8), 64, 0, stream>>>(qkvh, attnoh);
    gemm(attnoh, wt_dp_wo + (size_t)l * 512 * 512, nullptr, x_dp, x_dp, nullptr, DP_ROWS, 512, 512, 0);
    layernorm512<<<DP_ROWS, 64, 0, stream>>>(x_dp, xnh, dp_ln2g + l * 512, dp_ln2b + l * 512);
    gemm(xnh, wt_dp_w1 + (size_t)l * 2048 * 512, dp_b1 + l * 2048, nullptr, nullptr, ffh, DP_ROWS, 2048, 512, 1);
    gemm(ffh, wt_dp_w2 + (size_t)l * 512 * 2048, dp_b2 + l * 512, x_dp, x_dp, nullptr, DP_ROWS, 512, 2048, 0);
  }
  layernorm512<<<DP_ROWS, 64, 0, stream>>>(x_dp, xnh, dp_lnfg, dp_lnfb);
  gather_rows<<<OUT_ROWS, 128, 0, stream>>>(xnh, dtgh);
  gemm(dtgh, wt_logit, b_logit, nullptr, (float*)d_out, nullptr, OUT_ROWS, VOCABN, 512, 0);
}

// Round 5
// 1274.666 us; speedup vs baseline: 5.0978x; 1.2942x over previous
//
#include <hip/hip_runtime.h>
#include <math.h>

#define DIM 512
#define NSP 513                 // spatial seq len (MAX_S+1)
#define BATCHB 2
#define SP_ROWS (BATCHB*NSP)    // 1026
#define DP_ROWS (SP_ROWS*5)     // 5130
#define OUT_ROWS (BATCHB*2048)  // 4096
#define VOCABN 16384

typedef _Float16 f16x8 __attribute__((ext_vector_type(8)));
typedef _Float16 f16x4 __attribute__((ext_vector_type(4)));
typedef float    f32x4 __attribute__((ext_vector_type(4)));

// ---------------- fp16 MFMA GEMM v2: global_load_lds staging, 2-phase dbuf ----------------
// A[M][K] fp16 row-major, Bt[N][K] fp16 row-major (weights pre-transposed).
// BK=32, 256 threads = 4 waves in 2x2; each wave (BM/2)x(BN/2) via 16x16x32 frags.
template<int BM, int BN>
__global__ __launch_bounds__(256) void gemm2(
    const _Float16* __restrict__ A, const _Float16* __restrict__ Bt,
    const float* __restrict__ bias, const float* __restrict__ res,
    float* __restrict__ Cf, _Float16* __restrict__ Ch,
    int M, int N, int K, int act)
{
  constexpr int MF = BM / 32;   // frags per wave (M)
  constexpr int NF = BN / 32;   // frags per wave (N)
  __shared__ __align__(16) _Float16 As[2][BM * 32];
  __shared__ __align__(16) _Float16 Bs[2][BN * 32];
  int tid = threadIdx.x, wid = tid >> 6, lane = tid & 63;
  int lq = lane & 15, lg = lane >> 4;

  // XCD-aware bijective block swizzle (m204 formula)
  int nwg = gridDim.x * gridDim.y;
  int orig = blockIdx.y * gridDim.x + blockIdx.x;
  int qq = nwg >> 3, rr = nwg & 7;
  int xcd = orig & 7, loc = orig >> 3;
  int wgid = (xcd < rr ? xcd * (qq + 1) : rr * (qq + 1) + (xcd - rr) * qq) + loc;
  int bx = wgid % gridDim.x, by = wgid / gridDim.x;
  int row0 = by * BM, col0 = bx * BN;
  int wr = (wid >> 1) * (BM / 2), wc = (wid & 1) * (BN / 2);

  // stage one BK=32 tile of A and B into LDS buffer `cur` (linear layout [row][32])
  auto stage = [&](int cur, int t) {
    int k0 = t * 32;
#pragma unroll
    for (int j = 0; j < BM / 64; ++j) {
      int e = (j * 4 + wid) * 64 + lane;       // linear 16B-chunk index
      int row = e >> 2, kk = (e & 3) << 3;
      int gr = row0 + row; if (gr > M - 1) gr = M - 1;
      __builtin_amdgcn_global_load_lds(
          (const __attribute__((address_space(1))) void*)(A + (size_t)gr * K + k0 + kk),
          (__attribute__((address_space(3))) void*)(&As[cur][(j * 4 + wid) * 512]),
          16, 0, 0);
    }
#pragma unroll
    for (int j = 0; j < BN / 64; ++j) {
      int e = (j * 4 + wid) * 64 + lane;
      int row = e >> 2, kk = (e & 3) << 3;
      __builtin_amdgcn_global_load_lds(
          (const __attribute__((address_space(1))) void*)(Bt + (size_t)(col0 + row) * K + k0 + kk),
          (__attribute__((address_space(3))) void*)(&Bs[cur][(j * 4 + wid) * 512]),
          16, 0, 0);
    }
  };

  f32x4 acc[MF][NF];
#pragma unroll
  for (int m = 0; m < MF; ++m)
#pragma unroll
    for (int n = 0; n < NF; ++n) acc[m][n] = 0.f;

  const int nt = K >> 5;
  stage(0, 0);
  __syncthreads();
  int cur = 0;
  for (int t = 0; t < nt; ++t) {
    if (t + 1 < nt) stage(cur ^ 1, t + 1);   // prefetch in flight during compute
    f16x8 af[MF], bf[NF];
#pragma unroll
    for (int m = 0; m < MF; ++m)
      af[m] = *(const f16x8*)(&As[cur][(wr + m * 16 + lq) * 32 + lg * 8]);
#pragma unroll
    for (int n = 0; n < NF; ++n)
      bf[n] = *(const f16x8*)(&Bs[cur][(wc + n * 16 + lq) * 32 + lg * 8]);
#pragma unroll
    for (int m = 0; m < MF; ++m)
#pragma unroll
      for (int n = 0; n < NF; ++n)
        acc[m][n] = __builtin_amdgcn_mfma_f32_16x16x32_f16(af[m], bf[n], acc[m][n], 0, 0, 0);
    __syncthreads();                          // drains prefetch vmcnt + guards buf reuse
    cur ^= 1;
  }

#pragma unroll
  for (int m = 0; m < MF; ++m) {
#pragma unroll
    for (int n = 0; n < NF; ++n) {
      int row = row0 + wr + m * 16 + (lg << 2);
      int col = col0 + wc + n * 16 + lq;
      float bcol = bias ? bias[col] : 0.f;
#pragma unroll
      for (int r = 0; r < 4; ++r) {
        int rr2 = row + r;
        if (rr2 < M) {
          float v = acc[m][n][r] + bcol;
          if (act) v = 0.5f * v * (1.0f + erff(v * 0.70710678118f)); // exact gelu
          if (res) v += res[(size_t)rr2 * N + col];
          if (Cf) Cf[(size_t)rr2 * N + col] = v;
          if (Ch) Ch[(size_t)rr2 * N + col] = (_Float16)v;
        }
      }
    }
  }
}

// ---------------- fused causal flash attention (spatial), fp16 QKV ----------------
#define LDSK2 72
#define LDSV2 72
#define LDSP2 18
__global__ __launch_bounds__(256) void flash_sp(
    const _Float16* __restrict__ qkv, _Float16* __restrict__ O)
{
  __shared__ __align__(16) _Float16 K_lds[64 * LDSK2];
  __shared__ __align__(16) _Float16 V_lds[64 * LDSV2];   // transposed: [d][kv]
  __shared__ __align__(16) _Float16 P_lds[4][64 * LDSP2]; // per-wave [kv][q]
  int qt = blockIdx.x;       // 0..8
  int bh = blockIdx.y;       // b*8+h
  int b = bh >> 3, h = bh & 7;
  int tid = threadIdx.x, wid = tid >> 6, lane = tid & 63;
  int lq = lane & 15, lg = lane >> 4;
  int q0 = qt * 64 + wid * 16;
  int qg = q0 + lq;
  int qrow = b * NSP + (qg < NSP ? qg : NSP - 1);

  f16x8 Qf[2];
#pragma unroll
  for (int s = 0; s < 2; ++s) {
    Qf[s] = *(const f16x8*)(qkv + (size_t)qrow * 1536 + h * 64 + s * 32 + lg * 8);
#pragma unroll
    for (int i = 0; i < 8; ++i) Qf[s][i] = Qf[s][i] * (_Float16)0.125f;
  }

  float m = -3.0e38f, l = 0.f;
  f32x4 oacc[4];
#pragma unroll
  for (int n = 0; n < 4; ++n) oacc[n] = 0.f;

  int ntile = qt + 1;
  for (int t = 0; t < ntile; ++t) {
    int kv0 = t * 64;
#pragma unroll
    for (int j = 0; j < 2; ++j) {
      int idx = tid + j * 256;
      int row = idx >> 3, dc = (idx & 7) * 8;
      int kvr = kv0 + row;
      int grow = b * NSP + (kvr < NSP ? kvr : NSP - 1);
      f16x8 k8 = *(const f16x8*)(qkv + (size_t)grow * 1536 + 512 + h * 64 + dc);
      *(f16x8*)(&K_lds[row * LDSK2 + dc]) = k8;
      f16x8 v8 = *(const f16x8*)(qkv + (size_t)grow * 1536 + 1024 + h * 64 + dc);
#pragma unroll
      for (int e = 0; e < 8; ++e) V_lds[(dc + e) * LDSV2 + row] = v8[e];
    }
    __syncthreads();
    f32x4 st[4];
#pragma unroll
    for (int f = 0; f < 4; ++f) st[f] = 0.f;
#pragma unroll
    for (int s = 0; s < 2; ++s)
#pragma unroll
      for (int f = 0; f < 4; ++f) {
        f16x8 kf = *(const f16x8*)(&K_lds[(f * 16 + lq) * LDSK2 + s * 32 + lg * 8]);
        st[f] = __builtin_amdgcn_mfma_f32_16x16x32_f16(kf, Qf[s], st[f], 0, 0, 0);
      }
    float tmax = -3.0e38f;
#pragma unroll
    for (int f = 0; f < 4; ++f)
#pragma unroll
      for (int r = 0; r < 4; ++r) {
        int kvg = kv0 + f * 16 + lg * 4 + r;
        bool ok = (kvg <= qg) && (qg < NSP);
        if (ok) tmax = fmaxf(tmax, st[f][r]);
      }
    tmax = fmaxf(tmax, __shfl_xor(tmax, 16));
    tmax = fmaxf(tmax, __shfl_xor(tmax, 32));
    float mnew = fmaxf(m, tmax);
    float scale = __expf(m - mnew);
    float tsum = 0.f;
#pragma unroll
    for (int f = 0; f < 4; ++f)
#pragma unroll
      for (int r = 0; r < 4; ++r) {
        int kvg = kv0 + f * 16 + lg * 4 + r;
        bool ok = (kvg <= qg) && (qg < NSP);
        float p = ok ? __expf(st[f][r] - mnew) : 0.f;
        tsum += p;
        P_lds[wid][(f * 16 + lg * 4 + r) * LDSP2 + lq] = (_Float16)p;
      }
    tsum += __shfl_xor(tsum, 16);
    tsum += __shfl_xor(tsum, 32);
    l = l * scale + tsum;
    m = mnew;
#pragma unroll
    for (int n = 0; n < 4; ++n)
#pragma unroll
      for (int r = 0; r < 4; ++r) oacc[n][r] *= scale;
#pragma unroll
    for (int s = 0; s < 2; ++s) {
      f16x8 pf;
#pragma unroll
      for (int i = 0; i < 8; ++i) pf[i] = P_lds[wid][(s * 32 + lg * 8 + i) * LDSP2 + lq];
#pragma unroll
      for (int n = 0; n < 4; ++n) {
        f16x8 vf = *(const f16x8*)(&V_lds[(n * 16 + lq) * LDSV2 + s * 32 + lg * 8]);
        oacc[n] = __builtin_amdgcn_mfma_f32_16x16x32_f16(vf, pf, oacc[n], 0, 0, 0);
      }
    }
    __syncthreads();
  }
  if (qg < NSP) {
    float invl = 1.0f / l;
    _Float16* orow = O + (size_t)(b * NSP + qg) * 512 + h * 64;
#pragma unroll
    for (int n = 0; n < 4; ++n)
#pragma unroll
      for (int r = 0; r < 4; ++r)
        orow[n * 16 + lg * 4 + r] = (_Float16)(oacc[n][r] * invl);
  }
}

// ---------------- weight convert + transpose: W[L][K][N] f32 -> Wt[L][N][K] fp16 ----------------
__global__ __launch_bounds__(256) void cvt_wt(
    const float* __restrict__ W, _Float16* __restrict__ Wt, int K, int N)
{
  __shared__ float t[32][33];
  size_t lw = (size_t)blockIdx.z * K * N;
  int k0 = blockIdx.y * 32, n0 = blockIdx.x * 32;
  int tx = threadIdx.x & 31, ty = threadIdx.x >> 5;
#pragma unroll
  for (int r = ty; r < 32; r += 8) t[r][tx] = W[lw + (size_t)(k0 + r) * N + n0 + tx];
  __syncthreads();
#pragma unroll
  for (int r = ty; r < 32; r += 8) Wt[lw + (size_t)(n0 + r) * K + k0 + tx] = (_Float16)t[tx][r];
}

// ---------------- LayerNorm over 512, one wave per row; f32 in, fp16 out ----------------
__global__ __launch_bounds__(64) void layernorm512(
    const float* __restrict__ in, _Float16* __restrict__ out,
    const float* __restrict__ g, const float* __restrict__ bb)
{
  int row = blockIdx.x;
  int t = threadIdx.x;
  const float* x = in + (size_t)row * DIM;
  float xa[8];
  *(float4*)(xa)     = *(const float4*)(x + t * 4);
  *(float4*)(xa + 4) = *(const float4*)(x + 256 + t * 4);
  float s = 0.f, sq = 0.f;
#pragma unroll
  for (int i = 0; i < 8; ++i) { s += xa[i]; sq += xa[i] * xa[i]; }
#pragma unroll
  for (int off = 32; off; off >>= 1) { s += __shfl_xor(s, off); sq += __shfl_xor(sq, off); }
  float mean = s * (1.f / 512.f);
  float var = sq * (1.f / 512.f) - mean * mean;
  float rs = rsqrtf(var + 1e-5f);
  float ga[8], ba[8];
  *(float4*)(ga)     = *(const float4*)(g + t * 4);
  *(float4*)(ga + 4) = *(const float4*)(g + 256 + t * 4);
  *(float4*)(ba)     = *(const float4*)(bb + t * 4);
  *(float4*)(ba + 4) = *(const float4*)(bb + 256 + t * 4);
  f16x4 o0, o1;
#pragma unroll
  for (int i = 0; i < 4; ++i) o0[i] = (_Float16)((xa[i] - mean) * rs * ga[i] + ba[i]);
#pragma unroll
  for (int i = 0; i < 4; ++i) o1[i] = (_Float16)((xa[i + 4] - mean) * rs * ga[i + 4] + ba[i + 4]);
  _Float16* y = out + (size_t)row * DIM;
  *(f16x4*)(y + t * 4)       = o0;
  *(f16x4*)(y + 256 + t * 4) = o1;
}

// ---------------- Embedding ----------------
__global__ __launch_bounds__(128) void embed_tokens(
    const int* __restrict__ ids, const float* __restrict__ tok_emb,
    const float* __restrict__ dp_pos, float* __restrict__ tokens)
{
  int r = blockIdx.x;
  int dpt = r & 3;
  int id = ids[r];
  int c = threadIdx.x * 4;
  float4 e = *(const float4*)(tok_emb + (size_t)id * 512 + c);
  float4 p = *(const float4*)(dp_pos + dpt * 512 + c);
  float4 o = make_float4(e.x + p.x, e.y + p.y, e.z + p.z, e.w + p.w);
  *(float4*)(tokens + (size_t)r * 512 + c) = o;
}

// ---------------- spatial input rows ----------------
__global__ __launch_bounds__(128) void spatial_init(
    const float* __restrict__ tokens, const float* __restrict__ sp_pos,
    const float* __restrict__ start_tok, float* __restrict__ x_sp)
{
  int r = blockIdx.x;
  int b = r / NSP, s = r % NSP;
  int c = threadIdx.x * 4;
  float4 o;
  if (s == 0) {
    o = *(const float4*)(start_tok + c);
  } else {
    int s0 = s - 1;
    const float* tb = tokens + ((size_t)(b * 512 + s0) * 4) * 512 + c;
    float4 t0 = *(const float4*)(tb);
    float4 t1 = *(const float4*)(tb + 512);
    float4 t2 = *(const float4*)(tb + 1024);
    float4 t3 = *(const float4*)(tb + 1536);
    float4 pp = *(const float4*)(sp_pos + (size_t)s0 * 512 + c);
    o = make_float4(t0.x + t1.x + t2.x + t3.x + pp.x,
                    t0.y + t1.y + t2.y + t3.y + pp.y,
                    t0.z + t1.z + t2.z + t3.z + pp.z,
                    t0.w + t1.w + t2.w + t3.w + pp.w);
  }
  *(float4*)(x_sp + (size_t)r * 512 + c) = o;
}

// ---------------- depth attention (N=5), one wave per (r,h); fp16 in/out ----------------
__global__ __launch_bounds__(64) void attn_dp(
    const _Float16* __restrict__ qkv, _Float16* __restrict__ O)
{
  int r = blockIdx.x;
  int h = blockIdx.y;
  int d = threadIdx.x;
  const _Float16* base = qkv + (size_t)r * 5 * 1536 + h * 64 + d;
  float q[5], k[5], v[5];
#pragma unroll
  for (int p = 0; p < 5; ++p) {
    q[p] = (float)base[p * 1536] * 0.125f;
    k[p] = (float)base[p * 1536 + 512];
    v[p] = (float)base[p * 1536 + 1024];
  }
#pragma unroll
  for (int i = 0; i < 5; ++i) {
    float s[5];
    float mx = -3.0e38f;
    for (int j = 0; j <= i; ++j) {
      float part = q[i] * k[j];
#pragma unroll
      for (int off = 32; off; off >>= 1) part += __shfl_xor(part, off);
      s[j] = part;
      mx = fmaxf(mx, part);
    }
    float sum = 0.f;
    for (int j = 0; j <= i; ++j) { s[j] = expf(s[j] - mx); sum += s[j]; }
    float invs = 1.0f / sum;
    float o = 0.f;
    for (int j = 0; j <= i; ++j) o += s[j] * v[j];
    O[((size_t)r * 5 + i) * 512 + h * 64 + d] = (_Float16)(o * invs);
  }
}

// ---------------- build depth-transformer input ----------------
__global__ __launch_bounds__(128) void build_dt(
    const _Float16* __restrict__ sp_final, const float* __restrict__ tokens,
    float* __restrict__ x_dp)
{
  int row = blockIdx.x;
  int r = row / 5, cpos = row % 5;
  int c = threadIdx.x * 4;
  float4 o = make_float4(0.f, 0.f, 0.f, 0.f);
  if (cpos == 0) {
    f16x4 hv = *(const f16x4*)(sp_final + (size_t)r * 512 + c);
    o = make_float4((float)hv[0], (float)hv[1], (float)hv[2], (float)hv[3]);
  } else {
    int b = r / NSP, sp = r % NSP;
    if (sp < 512)
      o = *(const float4*)(tokens + ((size_t)((b * 512 + sp) * 4 + (cpos - 1))) * 512 + c);
  }
  *(float4*)(x_dp + (size_t)row * 512 + c) = o;
}

// ---------------- gather rows needed for logits ----------------
__global__ __launch_bounds__(128) void gather_rows(
    const _Float16* __restrict__ xn, _Float16* __restrict__ dtg)
{
  int m = blockIdx.x;
  int b = m >> 11;
  int t = 1 + (m & 2047);
  int c = threadIdx.x * 4;
  *(f16x4*)(dtg + (size_t)m * 512 + c) =
      *(const f16x4*)(xn + ((size_t)b * 2565 + t) * 512 + c);
}

extern "C" void kernel_launch(void* const* d_in, const int* in_sizes, int n_in,
                              void* d_out, int out_size, void* d_ws, size_t ws_size,
                              hipStream_t stream)
{
  const int*   ids       = (const int*)  d_in[0];
  const float* tok_emb   = (const float*)d_in[1];
  const float* start_tok = (const float*)d_in[2];
  const float* sp_pos    = (const float*)d_in[3];
  const float* dp_pos    = (const float*)d_in[4];
  const float* w_logit   = (const float*)d_in[5];
  const float* b_logit   = (const float*)d_in[6];
  const float* sp_ln1g = (const float*)d_in[7];
  const float* sp_ln1b = (const float*)d_in[8];
  const float* sp_qkv  = (const float*)d_in[9];
  const float* sp_wo   = (const float*)d_in[10];
  const float* sp_ln2g = (const float*)d_in[11];
  const float* sp_ln2b = (const float*)d_in[12];
  const float* sp_w1   = (const float*)d_in[13];
  const float* sp_b1   = (const float*)d_in[14];
  const float* sp_w2   = (const float*)d_in[15];
  const float* sp_b2   = (const float*)d_in[16];
  const float* sp_lnfg = (const float*)d_in[17];
  const float* sp_lnfb = (const float*)d_in[18];
  const float* dp_ln1g = (const float*)d_in[19];
  const float* dp_ln1b = (const float*)d_in[20];
  const float* dp_qkv  = (const float*)d_in[21];
  const float* dp_wo   = (const float*)d_in[22];
  const float* dp_ln2g = (const float*)d_in[23];
  const float* dp_ln2b = (const float*)d_in[24];
  const float* dp_w1   = (const float*)d_in[25];
  const float* dp_b1   = (const float*)d_in[26];
  const float* dp_w2   = (const float*)d_in[27];
  const float* dp_b2   = (const float*)d_in[28];
  const float* dp_lnfg = (const float*)d_in[29];
  const float* dp_lnfb = (const float*)d_in[30];

  char* wsb = (char*)d_ws;
  size_t off = 0;
  auto alloc = [&](size_t bytes) { char* p = wsb + off; off += (bytes + 255) & ~(size_t)255; return p; };

  float* tokens = (float*)alloc((size_t)4096 * 512 * 4);
  float* x_sp   = (float*)alloc((size_t)SP_ROWS * 512 * 4);
  float* x_dp   = (float*)alloc((size_t)DP_ROWS * 512 * 4);
  _Float16* qkvh   = (_Float16*)alloc((size_t)DP_ROWS * 1536 * 2);
  _Float16* xnh    = (_Float16*)alloc((size_t)DP_ROWS * 512 * 2);
  _Float16* attnoh = (_Float16*)alloc((size_t)DP_ROWS * 512 * 2);
  _Float16* ffh    = (_Float16*)alloc((size_t)DP_ROWS * 2048 * 2);
  _Float16* dtgh   = (_Float16*)alloc((size_t)OUT_ROWS * 512 * 2);
  _Float16* wt_sp_qkv = (_Float16*)alloc((size_t)4 * 1536 * 512 * 2);
  _Float16* wt_sp_wo  = (_Float16*)alloc((size_t)4 * 512 * 512 * 2);
  _Float16* wt_sp_w1  = (_Float16*)alloc((size_t)4 * 2048 * 512 * 2);
  _Float16* wt_sp_w2  = (_Float16*)alloc((size_t)4 * 512 * 2048 * 2);
  _Float16* wt_dp_qkv = (_Float16*)alloc((size_t)2 * 1536 * 512 * 2);
  _Float16* wt_dp_wo  = (_Float16*)alloc((size_t)2 * 512 * 512 * 2);
  _Float16* wt_dp_w1  = (_Float16*)alloc((size_t)2 * 2048 * 512 * 2);
  _Float16* wt_dp_w2  = (_Float16*)alloc((size_t)2 * 512 * 2048 * 2);
  _Float16* wt_logit  = (_Float16*)alloc((size_t)16384 * 512 * 2);

  auto cvt = [&](const float* W, _Float16* Wt, int L, int K, int N) {
    cvt_wt<<<dim3(N / 32, K / 32, L), 256, 0, stream>>>(W, Wt, K, N);
  };
  cvt(sp_qkv, wt_sp_qkv, 4, 512, 1536);
  cvt(sp_wo,  wt_sp_wo,  4, 512, 512);
  cvt(sp_w1,  wt_sp_w1,  4, 512, 2048);
  cvt(sp_w2,  wt_sp_w2,  4, 2048, 512);
  cvt(dp_qkv, wt_dp_qkv, 2, 512, 1536);
  cvt(dp_wo,  wt_dp_wo,  2, 512, 512);
  cvt(dp_w1,  wt_dp_w1,  2, 512, 2048);
  cvt(dp_w2,  wt_dp_w2,  2, 2048, 512);
  cvt(w_logit, wt_logit, 1, 512, 16384);

  // variant: 0 = 128x128, 1 = 64x128, 2 = 64x64
  auto gemm = [&](const _Float16* A, const _Float16* Bt, const float* bias, const float* res,
                  float* Cf, _Float16* Ch, int M, int N, int K, int act, int variant) {
    if (variant == 0)
      gemm2<128,128><<<dim3(N / 128, (M + 127) / 128), 256, 0, stream>>>(A, Bt, bias, res, Cf, Ch, M, N, K, act);
    else if (variant == 1)
      gemm2<64,128><<<dim3(N / 128, (M + 63) / 64), 256, 0, stream>>>(A, Bt, bias, res, Cf, Ch, M, N, K, act);
    else
      gemm2<64,64><<<dim3(N / 64, (M + 63) / 64), 256, 0, stream>>>(A, Bt, bias, res, Cf, Ch, M, N, K, act);
  };

  embed_tokens<<<4096, 128, 0, stream>>>(ids, tok_emb, dp_pos, tokens);
  spatial_init<<<SP_ROWS, 128, 0, stream>>>(tokens, sp_pos, start_tok, x_sp);

  for (int l = 0; l < 4; ++l) {
    layernorm512<<<SP_ROWS, 64, 0, stream>>>(x_sp, xnh, sp_ln1g + l * 512, sp_ln1b + l * 512);
    gemm(xnh, wt_sp_qkv + (size_t)l * 1536 * 512, nullptr, nullptr, nullptr, qkvh, SP_ROWS, 1536, 512, 0, 1);
    flash_sp<<<dim3(9, 16), 256, 0, stream>>>(qkvh, attnoh);
    gemm(attnoh, wt_sp_wo + (size_t)l * 512 * 512, nullptr, x_sp, x_sp, nullptr, SP_ROWS, 512, 512, 0, 2);
    layernorm512<<<SP_ROWS, 64, 0, stream>>>(x_sp, xnh, sp_ln2g + l * 512, sp_ln2b + l * 512);
    gemm(xnh, wt_sp_w1 + (size_t)l * 2048 * 512, sp_b1 + l * 2048, nullptr, nullptr, ffh, SP_ROWS, 2048, 512, 1, 1);
    gemm(ffh, wt_sp_w2 + (size_t)l * 512 * 2048, sp_b2 + l * 512, x_sp, x_sp, nullptr, SP_ROWS, 512, 2048, 0, 2);
  }
  layernorm512<<<SP_ROWS, 64, 0, stream>>>(x_sp, xnh, sp_lnfg, sp_lnfb);
  build_dt<<<DP_ROWS, 128, 0, stream>>>(xnh, tokens, x_dp);

  for (int l = 0; l < 2; ++l) {
    layernorm512<<<DP_ROWS, 64, 0, stream>>>(x_dp, xnh, dp_ln1g + l * 512, dp_ln1b + l * 512);
    gemm(xnh, wt_dp_qkv + (size_t)l * 1536 * 512, nullptr, nullptr, nullptr, qkvh, DP_ROWS, 1536, 512, 0, 0);
    attn_dp<<<dim3(SP_ROWS, 8), 64, 0, stream>>>(qkvh, attnoh);
    gemm(attnoh, wt_dp_wo + (size_t)l * 512 * 512, nullptr, x_dp, x_dp, nullptr, DP_ROWS, 512, 512, 0, 1);
    layernorm512<<<DP_ROWS, 64, 0, stream>>>(x_dp, xnh, dp_ln2g + l * 512, dp_ln2b + l * 512);
    gemm(xnh, wt_dp_w1 + (size_t)l * 2048 * 512, dp_b1 + l * 2048, nullptr, nullptr, ffh, DP_ROWS, 2048, 512, 1, 0);
    gemm(ffh, wt_dp_w2 + (size_t)l * 512 * 2048, dp_b2 + l * 512, x_dp, x_dp, nullptr, DP_ROWS, 512, 2048, 0, 1);
  }
  layernorm512<<<DP_ROWS, 64, 0, stream>>>(x_dp, xnh, dp_lnfg, dp_lnfb);
  gather_rows<<<OUT_ROWS, 128, 0, stream>>>(xnh, dtgh);
  gemm(dtgh, wt_logit, b_logit, nullptr, (float*)d_out, nullptr, OUT_ROWS, VOCABN, 512, 0, 0);
}